// Round 2
// baseline (589.909 us; speedup 1.0000x reference)
//
#include <hip/hip_runtime.h>
#include <hip/hip_bf16.h>

typedef __bf16 bf16;
typedef __bf16 bf16x8 __attribute__((ext_vector_type(8)));
typedef float f32x4 __attribute__((ext_vector_type(4)));

#define N_B 4
#define T_S 2048
#define D_M 1024
#define H_N 16
#define D_K 64
#define D3 3072
#define NEG_BIG (-1e30f)

// ---------------- dtype detector ----------------
// Interpret low 16 bits of each 32-bit word of z as bf16. True-bf16 data:
// those are N(0,1) values, exponent in [100,140] essentially always.
// fp32 data: low 16 bits are random mantissa bits -> exponent uniform,
// ~84% fall outside [100,140]. flag=1 => inputs are fp32.
__global__ void detect_dtype(const unsigned int* __restrict__ w,
                             int* __restrict__ flag) {
    __shared__ int cnt[256];
    int t = threadIdx.x;
    int weird = 0;
    for (int i = t; i < 4096; i += 256) {
        unsigned int v = w[i];
        unsigned int lowexp = (v >> 7) & 0xFFu;
        if ((v & 0xFFFFu) != 0u && (lowexp < 100u || lowexp > 140u)) weird++;
    }
    cnt[t] = weird;
    __syncthreads();
    for (int s = 128; s > 0; s >>= 1) {
        if (t < s) cnt[t] += cnt[t + s];
        __syncthreads();
    }
    if (t == 0) *flag = (cnt[0] > 1024) ? 1 : 0;
}

// ---------------- transpose (LDS-tiled), flag-aware input ----------------
// out[c][r] = (bf16) in[r][c]; in is R x C (fp32 if *flagp else bf16).
__global__ __launch_bounds__(256) void transpose_any(const void* __restrict__ in,
                                                     bf16* __restrict__ out,
                                                     int R, int C,
                                                     const int* __restrict__ flagp) {
    __shared__ bf16 tile[32][33];
    const int f = *flagp;
    int c0 = blockIdx.x * 32, r0 = blockIdx.y * 32;
    int tx = threadIdx.x, ty = threadIdx.y;
    if (f) {
        const float* inf_ = (const float*)in;
        for (int i = 0; i < 4; ++i)
            tile[ty + i * 8][tx] = (bf16)inf_[(size_t)(r0 + ty + i * 8) * C + c0 + tx];
    } else {
        const bf16* inb = (const bf16*)in;
        for (int i = 0; i < 4; ++i)
            tile[ty + i * 8][tx] = inb[(size_t)(r0 + ty + i * 8) * C + c0 + tx];
    }
    __syncthreads();
    for (int i = 0; i < 4; ++i)
        out[(size_t)(c0 + ty + i * 8) * R + r0 + tx] = tile[tx][ty + i * 8];
}

// ---------------- GEMM: C[M][N] = A[M][K] @ Bt[N][K]^T ----------------
// 64x64 tile, BK=32, 4 waves 2x2, each wave 32x32 via 2x2 mfma_f32_16x16x32_bf16.
// A dtype: fp32 if (modeA && *flagp) else bf16. Bt always bf16 (workspace).
// C dtype: fp32 if (modeC && *flagp) else bf16.
__global__ __launch_bounds__(256) void gemm_bt(const void* __restrict__ A,
                                               const bf16* __restrict__ Bt,
                                               void* __restrict__ C,
                                               int M, int N, int K,
                                               const int* __restrict__ flagp,
                                               int modeA, int modeC) {
    __shared__ bf16 As[64 * 32];
    __shared__ bf16 Bs[64 * 32];
    const int f = *flagp;
    const int aF32 = modeA & f;
    const int cF32 = modeC & f;
    const int t = threadIdx.x;
    const int m0 = blockIdx.y * 64, n0 = blockIdx.x * 64;
    const int w = t >> 6, lane = t & 63, quad = lane >> 4, l15 = lane & 15;
    const int wr = (w >> 1) * 32, wc = (w & 1) * 32;

    f32x4 acc[2][2];
    const f32x4 zero4 = {0.f, 0.f, 0.f, 0.f};
    acc[0][0] = zero4; acc[0][1] = zero4; acc[1][0] = zero4; acc[1][1] = zero4;

    const int srow = t >> 2;
    const int sseg = (t & 3) * 8;
    const size_t aBase = (size_t)(m0 + srow) * K + sseg;
    const size_t bBase = (size_t)(n0 + srow) * K + sseg;
    const int sOff = srow * 32 + sseg;

    const bf16* Ab = (const bf16*)A;
    const float* Af = (const float*)A;

    for (int k0 = 0; k0 < K; k0 += 32) {
        __syncthreads();
        if (aF32) {
            bf16 tmp[8];
#pragma unroll
            for (int j = 0; j < 8; ++j) tmp[j] = (bf16)Af[aBase + k0 + j];
#pragma unroll
            for (int j = 0; j < 8; ++j) As[sOff + j] = tmp[j];
        } else {
            *(uint4*)(As + sOff) = *(const uint4*)(Ab + aBase + k0);
        }
        *(uint4*)(Bs + sOff) = *(const uint4*)(Bt + bBase + k0);
        __syncthreads();

        bf16x8 a0 = *(const bf16x8*)(As + (wr + l15) * 32 + quad * 8);
        bf16x8 a1 = *(const bf16x8*)(As + (wr + 16 + l15) * 32 + quad * 8);
        bf16x8 b0 = *(const bf16x8*)(Bs + (wc + l15) * 32 + quad * 8);
        bf16x8 b1 = *(const bf16x8*)(Bs + (wc + 16 + l15) * 32 + quad * 8);
        acc[0][0] = __builtin_amdgcn_mfma_f32_16x16x32_bf16(a0, b0, acc[0][0], 0, 0, 0);
        acc[0][1] = __builtin_amdgcn_mfma_f32_16x16x32_bf16(a0, b1, acc[0][1], 0, 0, 0);
        acc[1][0] = __builtin_amdgcn_mfma_f32_16x16x32_bf16(a1, b0, acc[1][0], 0, 0, 0);
        acc[1][1] = __builtin_amdgcn_mfma_f32_16x16x32_bf16(a1, b1, acc[1][1], 0, 0, 0);
    }

    // C/D layout: row = quad*4 + reg, col = l15 (m89/m91 verified)
    for (int fr = 0; fr < 2; ++fr)
        for (int fc = 0; fc < 2; ++fc)
            for (int r = 0; r < 4; ++r) {
                size_t idx = (size_t)(m0 + wr + fr * 16 + quad * 4 + r) * N
                           + (n0 + wc + fc * 16 + l15);
                if (cF32) ((float*)C)[idx] = acc[fr][fc][r];
                else      ((bf16*)C)[idx] = (bf16)acc[fr][fc][r];
            }
}

// ---------------- fused causal attention ----------------
// qkv: [N*T][3072] bf16 (q|k|v). attn_out: [N*T][1024] bf16.
// One block per (n, h, qtile64). 4 waves, each owns a 16-row Q strip.
#define LD72 72
__global__ __launch_bounds__(256) void attn_fused(const bf16* __restrict__ qkv,
                                                  bf16* __restrict__ attn_out) {
    __shared__ bf16 Qs[64 * LD72];
    __shared__ bf16 Ks[64 * LD72];
    __shared__ bf16 Vt[64 * LD72];      // Vt[d][kv]
    __shared__ bf16 Pl[4 * 16 * LD72];  // per-wave 16x64 P strip

    const int b = blockIdx.x;
    const int qt = b & 31;
    const int h = (b >> 5) & 15;
    const int n = b >> 9;
    const int t = threadIdx.x;
    const int w = t >> 6, lane = t & 63, quad = lane >> 4, l15 = lane & 15;
    const int q0 = qt * 64;
    const size_t rowBase = (size_t)n * T_S;

    for (int idx = t; idx < 512; idx += 256) {
        int r = idx >> 3, sg = (idx & 7) * 8;
        *(uint4*)(Qs + r * LD72 + sg) =
            *(const uint4*)(qkv + (rowBase + q0 + r) * D3 + h * D_K + sg);
    }

    float m_i[4], l_i[4];
    f32x4 oacc[4];
    const f32x4 zero4 = {0.f, 0.f, 0.f, 0.f};
    for (int r = 0; r < 4; ++r) { m_i[r] = NEG_BIG; l_i[r] = 0.f; }
    for (int fd = 0; fd < 4; ++fd) oacc[fd] = zero4;

    for (int kt = 0; kt <= qt; ++kt) {
        const int k0r = kt * 64;
        __syncthreads();
        for (int idx = t; idx < 512; idx += 256) {
            int r = idx >> 3, sg = (idx & 7) * 8;
            *(uint4*)(Ks + r * LD72 + sg) =
                *(const uint4*)(qkv + (rowBase + k0r + r) * D3 + D_M + h * D_K + sg);
        }
        for (int idx = t; idx < 4096; idx += 256) {
            int r = idx >> 6, d = idx & 63;
            Vt[d * LD72 + r] = qkv[(rowBase + k0r + r) * D3 + 2 * D_M + h * D_K + d];
        }
        __syncthreads();

        f32x4 sacc[4];
        for (int fc = 0; fc < 4; ++fc) sacc[fc] = zero4;
        for (int ks = 0; ks < 2; ++ks) {
            bf16x8 a = *(const bf16x8*)(Qs + (w * 16 + l15) * LD72 + quad * 8 + ks * 32);
            for (int fc = 0; fc < 4; ++fc) {
                bf16x8 bb = *(const bf16x8*)(Ks + (fc * 16 + l15) * LD72 + quad * 8 + ks * 32);
                sacc[fc] = __builtin_amdgcn_mfma_f32_16x16x32_bf16(a, bb, sacc[fc], 0, 0, 0);
            }
        }

        float sv[4][4];
        for (int fc = 0; fc < 4; ++fc)
            for (int r = 0; r < 4; ++r) {
                int col = k0r + fc * 16 + l15;
                int row = q0 + w * 16 + quad * 4 + r;
                float x = sacc[fc][r] * 0.125f;
                sv[fc][r] = (col > row) ? NEG_BIG : x;
            }

        float rmax[4];
        for (int r = 0; r < 4; ++r)
            rmax[r] = fmaxf(fmaxf(sv[0][r], sv[1][r]), fmaxf(sv[2][r], sv[3][r]));
        for (int msk = 1; msk < 16; msk <<= 1)
            for (int r = 0; r < 4; ++r)
                rmax[r] = fmaxf(rmax[r], __shfl_xor(rmax[r], msk, 64));

        float alpha[4];
        for (int r = 0; r < 4; ++r) {
            float mn = fmaxf(m_i[r], rmax[r]);
            alpha[r] = __expf(m_i[r] - mn);
            m_i[r] = mn;
            l_i[r] *= alpha[r];
        }
        for (int fd = 0; fd < 4; ++fd)
            for (int r = 0; r < 4; ++r) oacc[fd][r] *= alpha[r];

        float rsum[4] = {0.f, 0.f, 0.f, 0.f};
        for (int fc = 0; fc < 4; ++fc)
            for (int r = 0; r < 4; ++r) {
                float p = __expf(sv[fc][r] - m_i[r]);
                rsum[r] += p;
                Pl[(w * 16 + quad * 4 + r) * LD72 + fc * 16 + l15] = (bf16)p;
            }
        for (int msk = 1; msk < 16; msk <<= 1)
            for (int r = 0; r < 4; ++r) rsum[r] += __shfl_xor(rsum[r], msk, 64);
        for (int r = 0; r < 4; ++r) l_i[r] += rsum[r];

        for (int ks = 0; ks < 2; ++ks) {
            bf16x8 pa = *(const bf16x8*)(Pl + (w * 16 + l15) * LD72 + quad * 8 + ks * 32);
            for (int fd = 0; fd < 4; ++fd) {
                bf16x8 vb = *(const bf16x8*)(Vt + (fd * 16 + l15) * LD72 + quad * 8 + ks * 32);
                oacc[fd] = __builtin_amdgcn_mfma_f32_16x16x32_bf16(pa, vb, oacc[fd], 0, 0, 0);
            }
        }
    }

    for (int fd = 0; fd < 4; ++fd)
        for (int r = 0; r < 4; ++r) {
            int row = q0 + w * 16 + quad * 4 + r;
            int col = h * D_K + fd * 16 + l15;
            attn_out[(rowBase + row) * D_M + col] = (bf16)(oacc[fd][r] / l_i[r]);
        }
}

extern "C" void kernel_launch(void* const* d_in, const int* in_sizes, int n_in,
                              void* d_out, int out_size, void* d_ws, size_t ws_size,
                              hipStream_t stream) {
    const void* z    = d_in[0];   // [4,2048,1024]  fp32 or bf16
    const void* Wqkv = d_in[1];   // [1024,3072]
    const void* Wout = d_in[2];   // [1024,1024]

    char* ws = (char*)d_ws;
    int*  flag  = (int*)ws;                                   // 256 B header
    bf16* qkv   = (bf16*)(ws + 256);                          // 50,331,648 B
    bf16* attn  = (bf16*)(ws + 256 + 50331648);               // 16,777,216 B
    bf16* WqkvT = (bf16*)(ws + 256 + 50331648 + 16777216);    //  6,291,456 B
    bf16* WoutT = (bf16*)(ws + 256 + 50331648 + 16777216 + 6291456);  // 2,097,152 B

    detect_dtype<<<1, 256, 0, stream>>>((const unsigned int*)z, flag);

    transpose_any<<<dim3(D3 / 32, D_M / 32), dim3(32, 8), 0, stream>>>(Wqkv, WqkvT, D_M, D3, flag);
    transpose_any<<<dim3(D_M / 32, D_M / 32), dim3(32, 8), 0, stream>>>(Wout, WoutT, D_M, D_M, flag);

    // qkv = z @ Wqkv : [8192 x 3072]
    gemm_bt<<<dim3(D3 / 64, (N_B * T_S) / 64), 256, 0, stream>>>(
        z, WqkvT, qkv, N_B * T_S, D3, D_M, flag, 1, 0);

    attn_fused<<<dim3(N_B * H_N * (T_S / 64)), 256, 0, stream>>>(qkv, attn);

    // out = attn @ Wout : [8192 x 1024]
    gemm_bt<<<dim3(D_M / 64, (N_B * T_S) / 64), 256, 0, stream>>>(
        attn, WoutT, d_out, N_B * T_S, D_M, D_M, flag, 0, 1);
}

// Round 3
// 468.403 us; speedup vs baseline: 1.2594x; 1.2594x over previous
//
#include <hip/hip_runtime.h>
#include <hip/hip_bf16.h>

typedef __bf16 bf16;
typedef __bf16 bf16x8 __attribute__((ext_vector_type(8)));
typedef float f32x4 __attribute__((ext_vector_type(4)));

#define N_B 4
#define T_S 2048
#define D_M 1024
#define H_N 16
#define D_K 64
#define D3 3072
#define NEG_BIG (-1e30f)

__device__ __forceinline__ void gload_lds16(const bf16* g, bf16* l) {
    __builtin_amdgcn_global_load_lds((const __attribute__((address_space(1))) void*)g,
                                     (__attribute__((address_space(3))) void*)l, 16, 0, 0);
}

// ---------------- dtype detector ----------------
__global__ void detect_dtype(const unsigned int* __restrict__ w,
                             int* __restrict__ flag) {
    __shared__ int cnt[256];
    int t = threadIdx.x;
    int weird = 0;
    for (int i = t; i < 4096; i += 256) {
        unsigned int v = w[i];
        unsigned int lowexp = (v >> 7) & 0xFFu;
        if ((v & 0xFFFFu) != 0u && (lowexp < 100u || lowexp > 140u)) weird++;
    }
    cnt[t] = weird;
    __syncthreads();
    for (int s = 128; s > 0; s >>= 1) {
        if (t < s) cnt[t] += cnt[t + s];
        __syncthreads();
    }
    if (t == 0) *flag = (cnt[0] > 1024) ? 1 : 0;
}

// ---------------- transpose (LDS-tiled), flag-aware input ----------------
__global__ __launch_bounds__(256) void transpose_any(const void* __restrict__ in,
                                                     bf16* __restrict__ out,
                                                     int R, int C,
                                                     const int* __restrict__ flagp) {
    __shared__ bf16 tile[32][33];
    const int f = *flagp;
    int c0 = blockIdx.x * 32, r0 = blockIdx.y * 32;
    int tx = threadIdx.x, ty = threadIdx.y;
    if (f) {
        const float* inf_ = (const float*)in;
        for (int i = 0; i < 4; ++i)
            tile[ty + i * 8][tx] = (bf16)inf_[(size_t)(r0 + ty + i * 8) * C + c0 + tx];
    } else {
        const bf16* inb = (const bf16*)in;
        for (int i = 0; i < 4; ++i)
            tile[ty + i * 8][tx] = inb[(size_t)(r0 + ty + i * 8) * C + c0 + tx];
    }
    __syncthreads();
    for (int i = 0; i < 4; ++i)
        out[(size_t)(c0 + ty + i * 8) * R + r0 + tx] = tile[tx][ty + i * 8];
}

// ---------------- GEMM: C[M][N] = A[M][K] @ Bt[N][K]^T ----------------
// 128x128 tile, BK=32, 4 waves 2x2, each wave 64x64 via 4x4 mfma_f32_16x16x32_bf16
// modeA: 1 => A is fp32 when *flagp (inline convert). else bf16 via global_load_lds.
// modeC: 0 => bf16 stride N; 1 => fp32 stride N;
//        2 => split: cols<2048 -> bf16 qk (stride 2048); cols>=2048 -> Vt transposed
__global__ __launch_bounds__(256) void gemm128(const void* __restrict__ A,
                                               const bf16* __restrict__ Bt,
                                               void* __restrict__ C,
                                               bf16* __restrict__ Vt,
                                               int M, int N, int K,
                                               const int* __restrict__ flagp,
                                               int modeA, int modeC) {
    __shared__ bf16 As[128 * 32];
    __shared__ bf16 Bs[128 * 32];
    const int t = threadIdx.x;
    const int m0 = blockIdx.y * 128, n0 = blockIdx.x * 128;
    const int w = t >> 6, lane = t & 63, quad = lane >> 4, l15 = lane & 15;
    const int wr = (w >> 1) * 64, wc = (w & 1) * 64;
    const int aF32 = modeA && *flagp;

    f32x4 acc[4][4];
    const f32x4 zero4 = {0.f, 0.f, 0.f, 0.f};
    for (int i = 0; i < 4; ++i)
        for (int j = 0; j < 4; ++j) acc[i][j] = zero4;

    // global_load_lds staging indices: linear element-chunk id = i*256 + t
    const int lin0 = t, lin1 = t + 256;
    const int r0_ = lin0 >> 2, s0_ = (lin0 & 3) * 8;
    const int r1_ = lin1 >> 2, s1_ = (lin1 & 3) * 8;
    bf16* ldsA0 = As + (size_t)(w * 64) * 8;        // wave-uniform base, +lane*16B implicit
    bf16* ldsA1 = As + (size_t)(256 + w * 64) * 8;
    bf16* ldsB0 = Bs + (size_t)(w * 64) * 8;
    bf16* ldsB1 = Bs + (size_t)(256 + w * 64) * 8;

    // fp32-A staging indices: 2 rows x 8 elements per thread
    const int fr_ = t >> 2, fs_ = (t & 3) * 8;

    const bf16* Ab = (const bf16*)A;
    const float* Af = (const float*)A;

    for (int k0 = 0; k0 < K; k0 += 32) {
        __syncthreads();
        if (aF32) {
#pragma unroll
            for (int r2 = 0; r2 < 2; ++r2) {
                int row = fr_ + r2 * 64;
                const float* p = Af + (size_t)(m0 + row) * K + k0 + fs_;
                float4 u0 = *(const float4*)p;
                float4 u1 = *(const float4*)(p + 4);
                union { uint4 q; bf16 h[8]; } pk;
                pk.h[0] = (bf16)u0.x; pk.h[1] = (bf16)u0.y;
                pk.h[2] = (bf16)u0.z; pk.h[3] = (bf16)u0.w;
                pk.h[4] = (bf16)u1.x; pk.h[5] = (bf16)u1.y;
                pk.h[6] = (bf16)u1.z; pk.h[7] = (bf16)u1.w;
                *(uint4*)(As + row * 32 + fs_) = pk.q;
            }
        } else {
            gload_lds16(Ab + (size_t)(m0 + r0_) * K + k0 + s0_, ldsA0);
            gload_lds16(Ab + (size_t)(m0 + r1_) * K + k0 + s1_, ldsA1);
        }
        gload_lds16(Bt + (size_t)(n0 + r0_) * K + k0 + s0_, ldsB0);
        gload_lds16(Bt + (size_t)(n0 + r1_) * K + k0 + s1_, ldsB1);
        __syncthreads();

        bf16x8 af[4], bfv[4];
#pragma unroll
        for (int i = 0; i < 4; ++i)
            af[i] = *(const bf16x8*)(As + (wr + i * 16 + l15) * 32 + quad * 8);
#pragma unroll
        for (int j = 0; j < 4; ++j)
            bfv[j] = *(const bf16x8*)(Bs + (wc + j * 16 + l15) * 32 + quad * 8);
#pragma unroll
        for (int i = 0; i < 4; ++i)
#pragma unroll
            for (int j = 0; j < 4; ++j)
                acc[i][j] = __builtin_amdgcn_mfma_f32_16x16x32_bf16(af[i], bfv[j], acc[i][j], 0, 0, 0);
    }

    // epilogue — C/D layout: row = quad*4 + reg, col = l15 (m89/m91 verified)
    if (modeC == 2 && n0 >= 2048) {
        // pure-V tile: write transposed Vt[(nb*1024 + c)][T], 4 rows packed per store
        for (int i = 0; i < 4; ++i)
            for (int j = 0; j < 4; ++j) {
                int c = n0 + wc + j * 16 + l15 - 2048;
                int rowb = m0 + wr + i * 16 + quad * 4;
                int nb = rowb >> 11, tt = rowb & 2047;
                union { ushort4 q; bf16 h[4]; } pk;
                for (int r = 0; r < 4; ++r) pk.h[r] = (bf16)acc[i][j][r];
                *(ushort4*)(Vt + ((size_t)(nb * 1024 + c)) * T_S + tt) = pk.q;
            }
    } else {
        const int strideC = (modeC == 2) ? 2048 : N;
        for (int i = 0; i < 4; ++i)
            for (int j = 0; j < 4; ++j)
                for (int r = 0; r < 4; ++r) {
                    size_t idx = (size_t)(m0 + wr + i * 16 + quad * 4 + r) * strideC
                               + (n0 + wc + j * 16 + l15);
                    if (modeC == 1) ((float*)C)[idx] = acc[i][j][r];
                    else            ((bf16*)C)[idx] = (bf16)acc[i][j][r];
                }
    }
}

// ---------------- fused causal attention ----------------
// qk: [N*T][2048] bf16 (q|k). Vt_g: [(n*16+h)*64+d][T] bf16. attn_out: [N*T][1024] bf16.
#define LD72 72
__global__ __launch_bounds__(256) void attn_fused(const bf16* __restrict__ qk,
                                                  const bf16* __restrict__ Vt_g,
                                                  bf16* __restrict__ attn_out) {
    __shared__ bf16 Qs[64 * LD72];
    __shared__ bf16 Ks[64 * LD72];
    __shared__ bf16 Vt[64 * LD72];      // Vt[d][kv]
    __shared__ bf16 Pl[4 * 16 * LD72];  // per-wave 16x64 P strip

    const int b = blockIdx.x;
    const int qt = b & 31;
    const int h = (b >> 5) & 15;
    const int n = b >> 9;
    const int t = threadIdx.x;
    const int w = t >> 6, lane = t & 63, quad = lane >> 4, l15 = lane & 15;
    const int q0 = qt * 64;
    const size_t rowBase = (size_t)n * T_S;
    const bf16* VtH = Vt_g + (size_t)(n * 1024 + h * 64) * T_S;

    for (int idx = t; idx < 512; idx += 256) {
        int r = idx >> 3, sg = (idx & 7) * 8;
        *(uint4*)(Qs + r * LD72 + sg) =
            *(const uint4*)(qk + (rowBase + q0 + r) * 2048 + h * D_K + sg);
    }

    float m_i[4], l_i[4];
    f32x4 oacc[4];
    const f32x4 zero4 = {0.f, 0.f, 0.f, 0.f};
    for (int r = 0; r < 4; ++r) { m_i[r] = NEG_BIG; l_i[r] = 0.f; }
    for (int fd = 0; fd < 4; ++fd) oacc[fd] = zero4;

    for (int kt = 0; kt <= qt; ++kt) {
        const int k0r = kt * 64;
        __syncthreads();
        for (int idx = t; idx < 512; idx += 256) {
            int r = idx >> 3, sg = (idx & 7) * 8;
            *(uint4*)(Ks + r * LD72 + sg) =
                *(const uint4*)(qk + (rowBase + k0r + r) * 2048 + 1024 + h * D_K + sg);
        }
        for (int idx = t; idx < 512; idx += 256) {
            int d = idx >> 3, sg = (idx & 7) * 8;
            *(uint4*)(Vt + d * LD72 + sg) =
                *(const uint4*)(VtH + (size_t)d * T_S + k0r + sg);
        }
        __syncthreads();

        f32x4 sacc[4];
        for (int fc = 0; fc < 4; ++fc) sacc[fc] = zero4;
        for (int ks = 0; ks < 2; ++ks) {
            bf16x8 a = *(const bf16x8*)(Qs + (w * 16 + l15) * LD72 + quad * 8 + ks * 32);
            for (int fc = 0; fc < 4; ++fc) {
                bf16x8 bb = *(const bf16x8*)(Ks + (fc * 16 + l15) * LD72 + quad * 8 + ks * 32);
                sacc[fc] = __builtin_amdgcn_mfma_f32_16x16x32_bf16(a, bb, sacc[fc], 0, 0, 0);
            }
        }

        float sv[4][4];
        if (kt == qt) {
            for (int fc = 0; fc < 4; ++fc)
                for (int r = 0; r < 4; ++r) {
                    int col = k0r + fc * 16 + l15;
                    int row = q0 + w * 16 + quad * 4 + r;
                    float x = sacc[fc][r] * 0.125f;
                    sv[fc][r] = (col > row) ? NEG_BIG : x;
                }
        } else {
            for (int fc = 0; fc < 4; ++fc)
                for (int r = 0; r < 4; ++r)
                    sv[fc][r] = sacc[fc][r] * 0.125f;
        }

        float rmax[4];
        for (int r = 0; r < 4; ++r)
            rmax[r] = fmaxf(fmaxf(sv[0][r], sv[1][r]), fmaxf(sv[2][r], sv[3][r]));
        for (int msk = 1; msk < 16; msk <<= 1)
            for (int r = 0; r < 4; ++r)
                rmax[r] = fmaxf(rmax[r], __shfl_xor(rmax[r], msk, 64));

        float alpha[4];
        for (int r = 0; r < 4; ++r) {
            float mn = fmaxf(m_i[r], rmax[r]);
            alpha[r] = __expf(m_i[r] - mn);
            m_i[r] = mn;
            l_i[r] *= alpha[r];
        }
        for (int fd = 0; fd < 4; ++fd)
            for (int r = 0; r < 4; ++r) oacc[fd][r] *= alpha[r];

        float rsum[4] = {0.f, 0.f, 0.f, 0.f};
        for (int fc = 0; fc < 4; ++fc)
            for (int r = 0; r < 4; ++r) {
                float p = __expf(sv[fc][r] - m_i[r]);
                rsum[r] += p;
                Pl[(w * 16 + quad * 4 + r) * LD72 + fc * 16 + l15] = (bf16)p;
            }
        for (int msk = 1; msk < 16; msk <<= 1)
            for (int r = 0; r < 4; ++r) rsum[r] += __shfl_xor(rsum[r], msk, 64);
        for (int r = 0; r < 4; ++r) l_i[r] += rsum[r];

        for (int ks = 0; ks < 2; ++ks) {
            bf16x8 pa = *(const bf16x8*)(Pl + (w * 16 + l15) * LD72 + quad * 8 + ks * 32);
            for (int fd = 0; fd < 4; ++fd) {
                bf16x8 vb = *(const bf16x8*)(Vt + (fd * 16 + l15) * LD72 + quad * 8 + ks * 32);
                oacc[fd] = __builtin_amdgcn_mfma_f32_16x16x32_bf16(pa, vb, oacc[fd], 0, 0, 0);
            }
        }
    }

    for (int fd = 0; fd < 4; ++fd)
        for (int r = 0; r < 4; ++r) {
            int row = q0 + w * 16 + quad * 4 + r;
            int col = h * D_K + fd * 16 + l15;
            attn_out[(rowBase + row) * D_M + col] = (bf16)(oacc[fd][r] / l_i[r]);
        }
}

extern "C" void kernel_launch(void* const* d_in, const int* in_sizes, int n_in,
                              void* d_out, int out_size, void* d_ws, size_t ws_size,
                              hipStream_t stream) {
    const void* z    = d_in[0];   // [4,2048,1024]  fp32 (or bf16)
    const void* Wqkv = d_in[1];   // [1024,3072]
    const void* Wout = d_in[2];   // [1024,1024]

    char* ws = (char*)d_ws;
    int*  flag  = (int*)ws;                                    // 256 B header
    bf16* qk    = (bf16*)(ws + 256);                           // 33,554,432 B  [8192][2048]
    bf16* attn  = (bf16*)(ws + 256 + 33554432);                // 16,777,216 B
    bf16* WqkvT = (bf16*)(ws + 256 + 33554432 + 16777216);     //  6,291,456 B
    bf16* WoutT = (bf16*)(ws + 256 + 33554432 + 16777216 + 6291456);  // 2,097,152 B
    bf16* Vt_g  = (bf16*)(ws + 256 + 33554432 + 16777216 + 6291456 + 2097152);  // 16,777,216 B

    detect_dtype<<<1, 256, 0, stream>>>((const unsigned int*)z, flag);

    transpose_any<<<dim3(D3 / 32, D_M / 32), dim3(32, 8), 0, stream>>>(Wqkv, WqkvT, D_M, D3, flag);
    transpose_any<<<dim3(D_M / 32, D_M / 32), dim3(32, 8), 0, stream>>>(Wout, WoutT, D_M, D_M, flag);

    // qkv = z @ Wqkv : q|k -> qk buffer (stride 2048), v -> Vt_g transposed
    gemm128<<<dim3(D3 / 128, (N_B * T_S) / 128), 256, 0, stream>>>(
        z, WqkvT, qk, Vt_g, N_B * T_S, D3, D_M, flag, 1, 2);

    attn_fused<<<dim3(N_B * H_N * (T_S / 64)), 256, 0, stream>>>(qk, Vt_g, attn);

    // out = attn @ Wout : [8192 x 1024] fp32 out
    gemm128<<<dim3(D_M / 128, (N_B * T_S) / 128), 256, 0, stream>>>(
        attn, WoutT, d_out, Vt_g, N_B * T_S, D_M, D_M, flag, 0, 1);
}

// Round 4
// 348.502 us; speedup vs baseline: 1.6927x; 1.3440x over previous
//
#include <hip/hip_runtime.h>
#include <hip/hip_bf16.h>

typedef __bf16 bf16;
typedef __bf16 bf16x8 __attribute__((ext_vector_type(8)));
typedef float f32x4 __attribute__((ext_vector_type(4)));

#define N_B 4
#define T_S 2048
#define D_M 1024
#define H_N 16
#define D_K 64
#define D3 3072
#define NEG_BIG (-1e30f)

__device__ __forceinline__ void gload_lds16(const bf16* g, bf16* l) {
    __builtin_amdgcn_global_load_lds((const __attribute__((address_space(1))) void*)g,
                                     (__attribute__((address_space(3))) void*)l, 16, 0, 0);
}

// ---------------- dtype detector ----------------
__global__ void detect_dtype(const unsigned int* __restrict__ w,
                             int* __restrict__ flag) {
    __shared__ int cnt[256];
    int t = threadIdx.x;
    int weird = 0;
    for (int i = t; i < 4096; i += 256) {
        unsigned int v = w[i];
        unsigned int lowexp = (v >> 7) & 0xFFu;
        if ((v & 0xFFFFu) != 0u && (lowexp < 100u || lowexp > 140u)) weird++;
    }
    cnt[t] = weird;
    __syncthreads();
    for (int s = 128; s > 0; s >>= 1) {
        if (t < s) cnt[t] += cnt[t + s];
        __syncthreads();
    }
    if (t == 0) *flag = (cnt[0] > 1024) ? 1 : 0;
}

// ---------------- transpose (LDS-tiled), flag-aware input ----------------
__global__ __launch_bounds__(256) void transpose_any(const void* __restrict__ in,
                                                     bf16* __restrict__ out,
                                                     int R, int C,
                                                     const int* __restrict__ flagp) {
    __shared__ bf16 tile[32][33];
    const int f = *flagp;
    int c0 = blockIdx.x * 32, r0 = blockIdx.y * 32;
    int tx = threadIdx.x, ty = threadIdx.y;
    if (f) {
        const float* inf_ = (const float*)in;
        for (int i = 0; i < 4; ++i)
            tile[ty + i * 8][tx] = (bf16)inf_[(size_t)(r0 + ty + i * 8) * C + c0 + tx];
    } else {
        const bf16* inb = (const bf16*)in;
        for (int i = 0; i < 4; ++i)
            tile[ty + i * 8][tx] = inb[(size_t)(r0 + ty + i * 8) * C + c0 + tx];
    }
    __syncthreads();
    for (int i = 0; i < 4; ++i)
        out[(size_t)(c0 + ty + i * 8) * R + r0 + tx] = tile[tx][ty + i * 8];
}

// ---------------- GEMM: C[M][N] = A[M][K] @ Bt[N][K]^T ----------------
// 128x128 tile, BK=32, 4 waves 2x2, each wave 64x64 via 4x4 mfma_f32_16x16x32_bf16
// modeA: 1 => A is fp32 when *flagp (inline convert), else bf16 via global_load_lds.
// modeC: 0 => bf16 stride N; 1 => fp32 stride N;
//        2 => split: cols<1024 -> qk *0.125 (Q pre-scale); 1024..2047 -> qk;
//             cols>=2048 -> Vt transposed
__global__ __launch_bounds__(256) void gemm128(const void* __restrict__ A,
                                               const bf16* __restrict__ Bt,
                                               void* __restrict__ C,
                                               bf16* __restrict__ Vt,
                                               int M, int N, int K,
                                               const int* __restrict__ flagp,
                                               int modeA, int modeC) {
    __shared__ bf16 As[128 * 32];
    __shared__ bf16 Bs[128 * 32];
    const int t = threadIdx.x;
    const int m0 = blockIdx.y * 128, n0 = blockIdx.x * 128;
    const int w = t >> 6, lane = t & 63, quad = lane >> 4, l15 = lane & 15;
    const int wr = (w >> 1) * 64, wc = (w & 1) * 64;
    const int aF32 = modeA && *flagp;

    f32x4 acc[4][4];
    const f32x4 zero4 = {0.f, 0.f, 0.f, 0.f};
    for (int i = 0; i < 4; ++i)
        for (int j = 0; j < 4; ++j) acc[i][j] = zero4;

    const int lin0 = t, lin1 = t + 256;
    const int r0_ = lin0 >> 2, s0_ = (lin0 & 3) * 8;
    const int r1_ = lin1 >> 2, s1_ = (lin1 & 3) * 8;
    bf16* ldsA0 = As + (size_t)(w * 64) * 8;
    bf16* ldsA1 = As + (size_t)(256 + w * 64) * 8;
    bf16* ldsB0 = Bs + (size_t)(w * 64) * 8;
    bf16* ldsB1 = Bs + (size_t)(256 + w * 64) * 8;

    const int fr_ = t >> 2, fs_ = (t & 3) * 8;

    const bf16* Ab = (const bf16*)A;
    const float* Af = (const float*)A;

    for (int k0 = 0; k0 < K; k0 += 32) {
        __syncthreads();
        if (aF32) {
#pragma unroll
            for (int r2 = 0; r2 < 2; ++r2) {
                int row = fr_ + r2 * 64;
                const float* p = Af + (size_t)(m0 + row) * K + k0 + fs_;
                float4 u0 = *(const float4*)p;
                float4 u1 = *(const float4*)(p + 4);
                union { uint4 q; bf16 h[8]; } pk;
                pk.h[0] = (bf16)u0.x; pk.h[1] = (bf16)u0.y;
                pk.h[2] = (bf16)u0.z; pk.h[3] = (bf16)u0.w;
                pk.h[4] = (bf16)u1.x; pk.h[5] = (bf16)u1.y;
                pk.h[6] = (bf16)u1.z; pk.h[7] = (bf16)u1.w;
                *(uint4*)(As + row * 32 + fs_) = pk.q;
            }
        } else {
            gload_lds16(Ab + (size_t)(m0 + r0_) * K + k0 + s0_, ldsA0);
            gload_lds16(Ab + (size_t)(m0 + r1_) * K + k0 + s1_, ldsA1);
        }
        gload_lds16(Bt + (size_t)(n0 + r0_) * K + k0 + s0_, ldsB0);
        gload_lds16(Bt + (size_t)(n0 + r1_) * K + k0 + s1_, ldsB1);
        __syncthreads();

        bf16x8 af[4], bfv[4];
#pragma unroll
        for (int i = 0; i < 4; ++i)
            af[i] = *(const bf16x8*)(As + (wr + i * 16 + l15) * 32 + quad * 8);
#pragma unroll
        for (int j = 0; j < 4; ++j)
            bfv[j] = *(const bf16x8*)(Bs + (wc + j * 16 + l15) * 32 + quad * 8);
#pragma unroll
        for (int i = 0; i < 4; ++i)
#pragma unroll
            for (int j = 0; j < 4; ++j)
                acc[i][j] = __builtin_amdgcn_mfma_f32_16x16x32_bf16(af[i], bfv[j], acc[i][j], 0, 0, 0);
    }

    if (modeC == 2 && n0 >= 2048) {
        // V tile: write transposed Vt[(nb*1024 + c)][T], 4 rows packed per store
        for (int i = 0; i < 4; ++i)
            for (int j = 0; j < 4; ++j) {
                int c = n0 + wc + j * 16 + l15 - 2048;
                int rowb = m0 + wr + i * 16 + quad * 4;
                int nb = rowb >> 11, tt = rowb & 2047;
                union { ushort4 q; bf16 h[4]; } pk;
                for (int r = 0; r < 4; ++r) pk.h[r] = (bf16)acc[i][j][r];
                *(ushort4*)(Vt + ((size_t)(nb * 1024 + c)) * T_S + tt) = pk.q;
            }
    } else {
        const int strideC = (modeC == 2) ? 2048 : N;
        const float scl = (modeC == 2 && n0 < 1024) ? 0.125f : 1.0f;  // Q pre-scale
        for (int i = 0; i < 4; ++i)
            for (int j = 0; j < 4; ++j)
                for (int r = 0; r < 4; ++r) {
                    size_t idx = (size_t)(m0 + wr + i * 16 + quad * 4 + r) * strideC
                               + (n0 + wc + j * 16 + l15);
                    if (modeC == 1) ((float*)C)[idx] = acc[i][j][r];
                    else            ((bf16*)C)[idx] = (bf16)(acc[i][j][r] * scl);
                }
    }
}

// ---------------- fused causal attention, S^T form, barrier-free ----------------
// qk: [N*T][2048] bf16 (q*0.125 | k). Vt_g: [(n*16+h)*64+d][T] bf16.
// attn_out: [N*T][1024] bf16. Grid 1024 = 64 heads x 16 q-tiles(128); 4 waves,
// each wave independently owns 32 q rows. No __syncthreads anywhere.
#define LDP 72
__global__ __launch_bounds__(256) void attn_fused(const bf16* __restrict__ qk,
                                                  const bf16* __restrict__ Vt_g,
                                                  bf16* __restrict__ attn_out) {
    __shared__ bf16 Pl[4 * 32 * LDP];   // per-wave private 32x64 P strip

    const int b = blockIdx.x;
    const int head = b & 63;            // n*16+h
    const int qt = 15 - (b >> 6);       // heavy q-tiles dispatch first
    const int n = head >> 4, h = head & 15;
    const int t = threadIdx.x;
    const int w = t >> 6, lane = t & 63, qd = lane >> 4, l15 = lane & 15;
    const int q0w = qt * 128 + w * 32;  // this wave's q base (32 rows)
    const size_t rowBase = (size_t)n * T_S;
    const bf16* Kb = qk + 1024 + h * 64;
    const bf16* Qb = qk + h * 64;
    const bf16* VtH = Vt_g + (size_t)(head * 64) * T_S;
    bf16* Plw = Pl + w * 32 * LDP;

    // persistent Q b-frags (pre-scaled by 0.125 in GEMM1): [qhalf][ks]
    bf16x8 bQ[2][2];
#pragma unroll
    for (int qh = 0; qh < 2; ++qh)
#pragma unroll
        for (int ks = 0; ks < 2; ++ks)
            bQ[qh][ks] = *(const bf16x8*)(Qb + (rowBase + q0w + qh * 16 + l15) * 2048
                                          + ks * 32 + qd * 8);

    float m_i[2] = {NEG_BIG, NEG_BIG}, l_i[2] = {0.f, 0.f};
    f32x4 oacc[2][4];
    const f32x4 zero4 = {0.f, 0.f, 0.f, 0.f};
#pragma unroll
    for (int qh = 0; qh < 2; ++qh)
#pragma unroll
        for (int fd = 0; fd < 4; ++fd) oacc[qh][fd] = zero4;

    const int ktmax = (q0w + 31) >> 6;
    for (int kt = 0; kt <= ktmax; ++kt) {
        const int k0r = kt * 64;

        // S^T[kv][q] = K @ Q^T : frags fc along kv, per qhalf
        f32x4 sacc[2][4];
#pragma unroll
        for (int qh = 0; qh < 2; ++qh)
#pragma unroll
            for (int fc = 0; fc < 4; ++fc) sacc[qh][fc] = zero4;
#pragma unroll
        for (int ks = 0; ks < 2; ++ks) {
            bf16x8 aK[4];
#pragma unroll
            for (int fc = 0; fc < 4; ++fc)
                aK[fc] = *(const bf16x8*)(Kb + (rowBase + k0r + fc * 16 + l15) * 2048
                                          + ks * 32 + qd * 8);
#pragma unroll
            for (int fc = 0; fc < 4; ++fc) {
                sacc[0][fc] = __builtin_amdgcn_mfma_f32_16x16x32_bf16(aK[fc], bQ[0][ks], sacc[0][fc], 0, 0, 0);
                sacc[1][fc] = __builtin_amdgcn_mfma_f32_16x16x32_bf16(aK[fc], bQ[1][ks], sacc[1][fc], 0, 0, 0);
            }
        }

        // causal mask: kv > q  (kv = k0r + fc*16 + qd*4 + r ; q = q0w + qh*16 + l15)
        if (k0r + 63 > q0w) {
#pragma unroll
            for (int qh = 0; qh < 2; ++qh) {
                int q = q0w + qh * 16 + l15;
#pragma unroll
                for (int fc = 0; fc < 4; ++fc)
#pragma unroll
                    for (int r = 0; r < 4; ++r) {
                        int kv = k0r + fc * 16 + qd * 4 + r;
                        if (kv > q) sacc[qh][fc][r] = NEG_BIG;
                    }
            }
        }

        // online softmax per qhalf (one scalar m/l per lane)
#pragma unroll
        for (int qh = 0; qh < 2; ++qh) {
            float mx = NEG_BIG;
#pragma unroll
            for (int fc = 0; fc < 4; ++fc)
#pragma unroll
                for (int r = 0; r < 4; ++r) mx = fmaxf(mx, sacc[qh][fc][r]);
            mx = fmaxf(mx, __shfl_xor(mx, 16, 64));
            mx = fmaxf(mx, __shfl_xor(mx, 32, 64));
            float mn = fmaxf(m_i[qh], mx);
            float alpha = __expf(m_i[qh] - mn);
            m_i[qh] = mn;

            float rs = 0.f;
#pragma unroll
            for (int fc = 0; fc < 4; ++fc) {
                union { ushort4 u; bf16 hh[4]; } pk;
#pragma unroll
                for (int r = 0; r < 4; ++r) {
                    float p = __expf(sacc[qh][fc][r] - mn);
                    rs += p;
                    pk.hh[r] = (bf16)p;
                }
                *(ushort4*)(Plw + (qh * 16 + l15) * LDP + fc * 16 + qd * 4) = pk.u;
            }
            rs += __shfl_xor(rs, 16, 64);
            rs += __shfl_xor(rs, 32, 64);
            l_i[qh] = l_i[qh] * alpha + rs;
#pragma unroll
            for (int fd = 0; fd < 4; ++fd) oacc[qh][fd] *= alpha;
        }

        // O^T += Vt @ P^T : a = Vt[d][kv] (global), b = P[q][kv] (wave-private LDS)
#pragma unroll
        for (int ks = 0; ks < 2; ++ks) {
            bf16x8 aV[4];
#pragma unroll
            for (int fd = 0; fd < 4; ++fd)
                aV[fd] = *(const bf16x8*)(VtH + (size_t)(fd * 16 + l15) * T_S
                                          + k0r + ks * 32 + qd * 8);
            bf16x8 bP0 = *(const bf16x8*)(Plw + l15 * LDP + ks * 32 + qd * 8);
            bf16x8 bP1 = *(const bf16x8*)(Plw + (16 + l15) * LDP + ks * 32 + qd * 8);
#pragma unroll
            for (int fd = 0; fd < 4; ++fd) {
                oacc[0][fd] = __builtin_amdgcn_mfma_f32_16x16x32_bf16(aV[fd], bP0, oacc[0][fd], 0, 0, 0);
                oacc[1][fd] = __builtin_amdgcn_mfma_f32_16x16x32_bf16(aV[fd], bP1, oacc[1][fd], 0, 0, 0);
            }
        }
    }

    // epilogue: O^T C-layout row d = fd*16+qd*4+r, col q = l15; /l; packed stores
#pragma unroll
    for (int qh = 0; qh < 2; ++qh) {
        float inv = 1.f / l_i[qh];
#pragma unroll
        for (int fd = 0; fd < 4; ++fd) {
            union { ushort4 u; bf16 hh[4]; } pk;
#pragma unroll
            for (int r = 0; r < 4; ++r) pk.hh[r] = (bf16)(oacc[qh][fd][r] * inv);
            *(ushort4*)(attn_out + (rowBase + q0w + qh * 16 + l15) * D_M
                        + h * D_K + fd * 16 + qd * 4) = pk.u;
        }
    }
}

extern "C" void kernel_launch(void* const* d_in, const int* in_sizes, int n_in,
                              void* d_out, int out_size, void* d_ws, size_t ws_size,
                              hipStream_t stream) {
    const void* z    = d_in[0];   // [4,2048,1024]  fp32 (or bf16)
    const void* Wqkv = d_in[1];   // [1024,3072]
    const void* Wout = d_in[2];   // [1024,1024]

    char* ws = (char*)d_ws;
    int*  flag  = (int*)ws;                                    // 256 B header
    bf16* qk    = (bf16*)(ws + 256);                           // 33,554,432 B  [8192][2048]
    bf16* attn  = (bf16*)(ws + 256 + 33554432);                // 16,777,216 B
    bf16* WqkvT = (bf16*)(ws + 256 + 33554432 + 16777216);     //  6,291,456 B
    bf16* WoutT = (bf16*)(ws + 256 + 33554432 + 16777216 + 6291456);  // 2,097,152 B
    bf16* Vt_g  = (bf16*)(ws + 256 + 33554432 + 16777216 + 6291456 + 2097152);  // 16,777,216 B

    detect_dtype<<<1, 256, 0, stream>>>((const unsigned int*)z, flag);

    transpose_any<<<dim3(D3 / 32, D_M / 32), dim3(32, 8), 0, stream>>>(Wqkv, WqkvT, D_M, D3, flag);
    transpose_any<<<dim3(D_M / 32, D_M / 32), dim3(32, 8), 0, stream>>>(Wout, WoutT, D_M, D_M, flag);

    // qkv = z @ Wqkv : q(*0.125)|k -> qk (stride 2048), v -> Vt_g transposed
    gemm128<<<dim3(D3 / 128, (N_B * T_S) / 128), 256, 0, stream>>>(
        z, WqkvT, qk, Vt_g, N_B * T_S, D3, D_M, flag, 1, 2);

    attn_fused<<<dim3(64 * (T_S / 128)), 256, 0, stream>>>(qk, Vt_g, attn);

    // out = attn @ Wout : [8192 x 1024] fp32 out
    gemm128<<<dim3(D_M / 128, (N_B * T_S) / 128), 256, 0, stream>>>(
        attn, WoutT, d_out, Vt_g, N_B * T_S, D_M, D_M, flag, 0, 1);
}